// Round 1
// 438.252 us; speedup vs baseline: 1.0490x; 1.0490x over previous
//
#include <hip/hip_runtime.h>
#include <hip/hip_bf16.h>

// Problem dims (fixed by the reference):
//   x: (256*14*14, 384) fp32  -> M = 50176, K = 384
//   W: (1536, 384) fp32       -> N = 1536 (row-major N x K, i.e. B^T layout)
//   out: (M, N) fp32
#define M_ROWS 50176
#define K_DIM  384
#define N_DIM  1536

typedef __bf16 bf16;
typedef bf16  bf16x8 __attribute__((ext_vector_type(8)));
typedef float f32x4  __attribute__((ext_vector_type(4)));

typedef __attribute__((address_space(1))) const void* addr1_cptr;
typedef __attribute__((address_space(3))) void*       addr3_ptr;

// Async global->LDS, 16B per lane. LDS dest = wave-uniform base + lane*16.
__device__ __forceinline__ void async_copy16(const void* g, void* l) {
    __builtin_amdgcn_global_load_lds((addr1_cptr)g, (addr3_ptr)l, 16, 0, 0);
}

// Fast exact GELU: 0.5*y*(1+erf(y/sqrt(2))) with A&S 7.1.26 erf
// (max |err| 1.5e-7 on erf -> negligible vs bf16 matmul noise).
// ~14 VALU ops vs ~25-30 for libm erff.
__device__ __forceinline__ float gelu_exact(float y) {
    const float ax = fabsf(y) * 0.70710678118654752f;   // |y|/sqrt(2)
    const float t  = __builtin_amdgcn_rcpf(1.0f + 0.3275911f * ax);
    const float p  = t * (0.254829592f +
                     t * (-0.284496736f +
                     t * (1.421413741f +
                     t * (-1.453152027f +
                     t * 1.061405429f))));
    const float e  = __expf(-ax * ax);
    const float er = copysignf(1.0f - p * e, y);        // erf(y/sqrt(2))
    const float h  = 0.5f * y;
    return h + h * er;                                  // 0.5y(1+erf)
}

// ---------------------------------------------------------------------------
// Kernel 1: LayerNorm over last dim (384), fp32 in -> bf16 out.
// One wave per row; lane holds 3 float2 (6 elems).
// ---------------------------------------------------------------------------
__global__ __launch_bounds__(256) void ln_kernel(
    const float* __restrict__ x, const float* __restrict__ gamma,
    const float* __restrict__ beta, bf16* __restrict__ xn) {
    const int t = threadIdx.x;
    const int wave = t >> 6, lane = t & 63;
    const long row = (long)blockIdx.x * 4 + wave;

    const float2* xr = (const float2*)(x + row * K_DIM);
    float2 v[3];
    v[0] = xr[lane];
    v[1] = xr[lane + 64];
    v[2] = xr[lane + 128];

    float s = v[0].x + v[0].y + v[1].x + v[1].y + v[2].x + v[2].y;
    float q = v[0].x * v[0].x + v[0].y * v[0].y + v[1].x * v[1].x +
              v[1].y * v[1].y + v[2].x * v[2].x + v[2].y * v[2].y;
#pragma unroll
    for (int off = 32; off > 0; off >>= 1) {
        s += __shfl_xor(s, off);
        q += __shfl_xor(q, off);
    }
    const float mean = s * (1.0f / K_DIM);
    const float var  = q * (1.0f / K_DIM) - mean * mean;
    const float rstd = rsqrtf(var + 1e-6f);

    const float2* g2 = (const float2*)gamma;
    const float2* b2 = (const float2*)beta;
    bf16* orow = xn + row * K_DIM;
#pragma unroll
    for (int i = 0; i < 3; ++i) {
        float2 g  = g2[lane + i * 64];
        float2 bb = b2[lane + i * 64];
        float y0 = (v[i].x - mean) * rstd * g.x + bb.x;
        float y1 = (v[i].y - mean) * rstd * g.y + bb.y;
        __hip_bfloat162 h;
        h.x = __float2bfloat16(y0);
        h.y = __float2bfloat16(y1);
        *(__hip_bfloat162*)(orow + (lane + i * 64) * 2) = h;
    }
}

// ---------------------------------------------------------------------------
// Kernel 2: W fp32 -> bf16 (1536*384 elems, 2 per thread)
// ---------------------------------------------------------------------------
__global__ __launch_bounds__(256) void wcvt_kernel(
    const float* __restrict__ W, bf16* __restrict__ Wb) {
    const int i = blockIdx.x * 256 + threadIdx.x;  // over float2, count 294912
    float2 v = ((const float2*)W)[i];
    __hip_bfloat162 h;
    h.x = __float2bfloat16(v.x);
    h.y = __float2bfloat16(v.y);
    ((__hip_bfloat162*)Wb)[i] = h;
}

// ---------------------------------------------------------------------------
// Kernel 3: GEMM C = A(M x K, bf16) @ W^T (W is N x K, bf16) + bias, GELU.
//
// 256x128 block tile, BK=32, 8 waves (4x2), each wave owns a 64x64 quadrant
// as 4x4 grid of 16x16x32 MFMA tiles (same verified fragment layout/swizzle
// as the previous passing kernel).
//
// Pipeline (T3-lite + T4 counted vmcnt, catalog §5.5):
//   ring-3 LDS (72 KB), stage tile kb+2 at the top of iteration kb,
//   ONE raw s_barrier per K-step, boundary wait = s_waitcnt vmcnt(3)
//   (never 0 in steady state) so the 3 prefetch loads of kb+2 stay in
//   flight across the barrier. lgkm waits for ds_read->MFMA are left to
//   the compiler (it emits fine-grained lgkmcnt, guide §5).
// Correctness audit:
//   - stage(kb+2) writes slot (kb-1)%3; all waves finished reading that
//     slot during kb-1 (their MFMAs consumed the reads before the
//     end-of-(kb-1) barrier, which precedes this issue in program order).
//   - per-wave vmcnt(3) at end of kb leaves only kb+2's 3 loads in
//     flight => own slices of tile kb+1 landed; barrier makes it mutual.
//   - "memory" clobber on the asm pins ds_reads/gloads on each side.
// __launch_bounds__(512,4): VGPR<=128 (acc 64 + frags 32 + addr ~20)
//   => 2 blocks/CU, so one block's epilogue/store drain overlaps the
//   other block's K-loop.
// ---------------------------------------------------------------------------
#define BM 256
#define BN 128
#define BK 32
#define NKT (K_DIM / BK)   // 12

__global__ __launch_bounds__(512, 4) void gemm_kernel(
    const bf16* __restrict__ A,    // [M][K]
    const bf16* __restrict__ B,    // [N][K]  (= W in bf16)
    const float* __restrict__ bias,
    float* __restrict__ out) {
    __shared__ __align__(16) bf16 Al[3][BM * BK];  // 3 x 16 KB
    __shared__ __align__(16) bf16 Bl[3][BN * BK];  // 3 x  8 KB

    const int t = threadIdx.x;
    const int wave = t >> 6, lane = t & 63;
    const int wr = wave >> 1, wc = wave & 1;     // 4x2 wave grid
    const int lr = lane & 15, quad = lane >> 4;  // MFMA lane decomposition
    const long m0 = (long)blockIdx.y * BM;
    const int  n0 = blockIdx.x * BN;

    // Staging sources (pre-swizzled global addresses; LDS stays linear).
    // Slot e (16B units): row = e>>2, slot_chunk = e&3 holds global chunk
    // gc = (e&3) ^ ((row>>1)&3). A: 1024 slots (2 insts), B: 512 (1 inst).
    const int e1 = 512 + t;
    const int r0 = t >> 2, r1 = e1 >> 2;
    const int c0 = (t & 3) ^ ((r0 >> 1) & 3);
    const int c1 = (e1 & 3) ^ ((r1 >> 1) & 3);
    const bf16* gA0 = A + (m0 + r0) * K_DIM + c0 * 8;
    const bf16* gA1 = A + (m0 + r1) * K_DIM + c1 * 8;
    const bf16* gB0 = B + (long)(n0 + r0) * K_DIM + c0 * 8;

    const int ldsOff0 = (wave * 64) * 16;        // wave-uniform dest (bytes)
    const int ldsOff1 = (512 + wave * 64) * 16;

#define STAGE(slot, kb)                                                   \
    do {                                                                  \
        async_copy16(gA0 + (kb) * BK, (char*)Al[slot] + ldsOff0);         \
        async_copy16(gA1 + (kb) * BK, (char*)Al[slot] + ldsOff1);         \
        async_copy16(gB0 + (kb) * BK, (char*)Bl[slot] + ldsOff0);         \
    } while (0)

    f32x4 acc[4][4];
#pragma unroll
    for (int i = 0; i < 4; ++i)
#pragma unroll
        for (int j = 0; j < 4; ++j)
            acc[i][j] = (f32x4){0.f, 0.f, 0.f, 0.f};

    // LDS read offsets: row r reads chunk quad swizzled by ((r>>1)&3);
    // 16-row fragment bases are multiples of 16 so only lr enters the XOR.
    const int sw   = (quad ^ ((lr >> 1) & 3)) * 8;
    const int aoff = (wr * 64 + lr) * BK + sw;
    const int boff = (wc * 64 + lr) * BK + sw;

    // Prologue: tiles 0,1 in flight; wait tile 0 (3 newer loads allowed).
    STAGE(0, 0);
    STAGE(1, 1);
    asm volatile("s_waitcnt vmcnt(3)" ::: "memory");
    __builtin_amdgcn_s_barrier();

#pragma unroll
    for (int kb = 0; kb < NKT; ++kb) {
        if (kb + 2 < NKT) STAGE((kb + 2) % 3, kb + 2);
        __builtin_amdgcn_sched_barrier(0);  // keep prefetch issue ahead

        const bf16* Ab = Al[kb % 3] + aoff;
        const bf16* Bb = Bl[kb % 3] + boff;
        bf16x8 a[4], b[4];
#pragma unroll
        for (int i = 0; i < 4; ++i) a[i] = *(const bf16x8*)(Ab + i * 16 * BK);
#pragma unroll
        for (int j = 0; j < 4; ++j) b[j] = *(const bf16x8*)(Bb + j * 16 * BK);

        __builtin_amdgcn_s_setprio(1);
#pragma unroll
        for (int i = 0; i < 4; ++i)
#pragma unroll
            for (int j = 0; j < 4; ++j)
                acc[i][j] = __builtin_amdgcn_mfma_f32_16x16x32_bf16(
                    a[i], b[j], acc[i][j], 0, 0, 0);
        __builtin_amdgcn_s_setprio(0);

        // Boundary: ensure tile kb+1 landed; keep kb+2's loads in flight.
        if (kb + 2 < NKT) {
            asm volatile("s_waitcnt vmcnt(3)" ::: "memory");
        } else if (kb + 1 < NKT) {
            asm volatile("s_waitcnt vmcnt(0)" ::: "memory");
        }
        if (kb + 1 < NKT) __builtin_amdgcn_s_barrier();
    }
#undef STAGE

    // Epilogue: C/D layout col = lane&15, row = quad*4 + reg [m89/m91].
    float bb[4];
#pragma unroll
    for (int j = 0; j < 4; ++j) bb[j] = bias[n0 + wc * 64 + j * 16 + lr];

#pragma unroll
    for (int i = 0; i < 4; ++i) {
        const long grow0 = m0 + wr * 64 + i * 16 + quad * 4;
#pragma unroll
        for (int j = 0; j < 4; ++j) {
            const int gcol = n0 + wc * 64 + j * 16 + lr;
#pragma unroll
            for (int r = 0; r < 4; ++r) {
                const float y = acc[i][j][r] + bb[j];
                __builtin_nontemporal_store(
                    gelu_exact(y), &out[(grow0 + r) * (long)N_DIM + gcol]);
            }
        }
    }
}

extern "C" void kernel_launch(void* const* d_in, const int* in_sizes, int n_in,
                              void* d_out, int out_size, void* d_ws, size_t ws_size,
                              hipStream_t stream) {
    (void)in_sizes; (void)n_in; (void)out_size; (void)ws_size;
    const float* x     = (const float*)d_in[0];
    const float* gamma = (const float*)d_in[1];
    const float* beta  = (const float*)d_in[2];
    const float* W     = (const float*)d_in[3];
    const float* b     = (const float*)d_in[4];
    float* out = (float*)d_out;

    // Workspace layout: xn bf16 [M][K] then Wb bf16 [N][K] (~39.7 MB total).
    bf16* xn = (bf16*)d_ws;
    bf16* Wb = (bf16*)((char*)d_ws + (size_t)M_ROWS * K_DIM * sizeof(bf16));

    ln_kernel<<<M_ROWS / 4, 256, 0, stream>>>(x, gamma, beta, xn);
    wcvt_kernel<<<(N_DIM * K_DIM / 2) / 256, 256, 0, stream>>>(W, Wb);

    dim3 grid(N_DIM / BN, M_ROWS / BM);
    gemm_kernel<<<grid, 512, 0, stream>>>(xn, Wb, b, out);
}

// Round 2
// 416.569 us; speedup vs baseline: 1.1036x; 1.0521x over previous
//
#include <hip/hip_runtime.h>
#include <hip/hip_bf16.h>

// Problem dims (fixed by the reference):
//   x: (256*14*14, 384) fp32  -> M = 50176, K = 384
//   W: (1536, 384) fp32       -> N = 1536 (row-major N x K, i.e. B^T layout)
//   out: (M, N) fp32
#define M_ROWS 50176
#define K_DIM  384
#define N_DIM  1536

typedef __bf16 bf16;
typedef bf16  bf16x8 __attribute__((ext_vector_type(8)));
typedef float f32x4  __attribute__((ext_vector_type(4)));

typedef __attribute__((address_space(1))) const void* addr1_cptr;
typedef __attribute__((address_space(3))) void*       addr3_ptr;

// Async global->LDS, 16B per lane. LDS dest = wave-uniform base + lane*16.
__device__ __forceinline__ void async_copy16(const void* g, void* l) {
    __builtin_amdgcn_global_load_lds((addr1_cptr)g, (addr3_ptr)l, 16, 0, 0);
}

// Fast exact GELU: 0.5*y*(1+erf(y/sqrt(2))) with A&S 7.1.26 erf
// (max |err| 1.5e-7 on erf -> negligible vs bf16 matmul noise).
__device__ __forceinline__ float gelu_exact(float y) {
    const float ax = fabsf(y) * 0.70710678118654752f;   // |y|/sqrt(2)
    const float t  = __builtin_amdgcn_rcpf(1.0f + 0.3275911f * ax);
    const float p  = t * (0.254829592f +
                     t * (-0.284496736f +
                     t * (1.421413741f +
                     t * (-1.453152027f +
                     t * 1.061405429f))));
    const float e  = __expf(-ax * ax);
    const float er = copysignf(1.0f - p * e, y);        // erf(y/sqrt(2))
    const float h  = 0.5f * y;
    return h + h * er;                                  // 0.5y(1+erf)
}

// ---------------------------------------------------------------------------
// Kernel 1: LayerNorm over last dim (384), fp32 in -> bf16 out.
// One wave per row; lane holds 3 float2 (6 elems).
// ---------------------------------------------------------------------------
__global__ __launch_bounds__(256) void ln_kernel(
    const float* __restrict__ x, const float* __restrict__ gamma,
    const float* __restrict__ beta, bf16* __restrict__ xn) {
    const int t = threadIdx.x;
    const int wave = t >> 6, lane = t & 63;
    const long row = (long)blockIdx.x * 4 + wave;

    const float2* xr = (const float2*)(x + row * K_DIM);
    float2 v[3];
    v[0] = xr[lane];
    v[1] = xr[lane + 64];
    v[2] = xr[lane + 128];

    float s = v[0].x + v[0].y + v[1].x + v[1].y + v[2].x + v[2].y;
    float q = v[0].x * v[0].x + v[0].y * v[0].y + v[1].x * v[1].x +
              v[1].y * v[1].y + v[2].x * v[2].x + v[2].y * v[2].y;
#pragma unroll
    for (int off = 32; off > 0; off >>= 1) {
        s += __shfl_xor(s, off);
        q += __shfl_xor(q, off);
    }
    const float mean = s * (1.0f / K_DIM);
    const float var  = q * (1.0f / K_DIM) - mean * mean;
    const float rstd = rsqrtf(var + 1e-6f);

    const float2* g2 = (const float2*)gamma;
    const float2* b2 = (const float2*)beta;
    bf16* orow = xn + row * K_DIM;
#pragma unroll
    for (int i = 0; i < 3; ++i) {
        float2 g  = g2[lane + i * 64];
        float2 bb = b2[lane + i * 64];
        float y0 = (v[i].x - mean) * rstd * g.x + bb.x;
        float y1 = (v[i].y - mean) * rstd * g.y + bb.y;
        __hip_bfloat162 h;
        h.x = __float2bfloat16(y0);
        h.y = __float2bfloat16(y1);
        *(__hip_bfloat162*)(orow + (lane + i * 64) * 2) = h;
    }
}

// ---------------------------------------------------------------------------
// Kernel 2: W fp32 -> bf16 (1536*384 elems, 2 per thread)
// ---------------------------------------------------------------------------
__global__ __launch_bounds__(256) void wcvt_kernel(
    const float* __restrict__ W, bf16* __restrict__ Wb) {
    const int i = blockIdx.x * 256 + threadIdx.x;  // over float2, count 294912
    float2 v = ((const float2*)W)[i];
    __hip_bfloat162 h;
    h.x = __float2bfloat16(v.x);
    h.y = __float2bfloat16(v.y);
    ((__hip_bfloat162*)Wb)[i] = h;
}

// ---------------------------------------------------------------------------
// Kernel 3: GEMM C = A(M x K, bf16) @ W^T (W is N x K, bf16) + bias, GELU.
//
// 256x128 block tile, BK=32, 8 waves (4x2), each wave a 64x64 quadrant as
// 4x4 grid of 16x16x32 MFMA tiles (verified fragment layout/swizzle).
//
// Pipeline: ring-3 LDS (72 KB), stage tile kb+2 at top of iteration kb,
// ONE raw s_barrier per K-step, boundary wait s_waitcnt vmcnt(3) (never 0
// in steady state). NO sched_barrier — m141 showed order-pinning defeats
// hipcc's own fine-grained lgkmcnt scheduling (874->510 TF); the bottom
// vmcnt asm ("memory" clobber) already keeps STAGE issue inside the step.
//
// XCD swizzle (T1): grid is (12,196) x-fast, so the 12 blocks sharing one
// 196KB A-panel are consecutive; chunked remap (nwg=2352 = 8*294, exactly
// divisible -> simple bijective form) puts them on ONE XCD back-to-back so
// the panel is fetched into one L2 and reused 12x instead of landing in
// ~8 different per-XCD L2s.
// ---------------------------------------------------------------------------
#define BM 256
#define BN 128
#define BK 32
#define NKT (K_DIM / BK)   // 12
#define GRID_X (N_DIM / BN)            // 12
#define GRID_Y (M_ROWS / BM)           // 196
#define NWG    (GRID_X * GRID_Y)       // 2352
#define WG_PER_XCD (NWG / 8)           // 294

__global__ __launch_bounds__(512, 4) void gemm_kernel(
    const bf16* __restrict__ A,    // [M][K]
    const bf16* __restrict__ B,    // [N][K]  (= W in bf16)
    const float* __restrict__ bias,
    float* __restrict__ out) {
    __shared__ __align__(16) bf16 Al[3][BM * BK];  // 3 x 16 KB
    __shared__ __align__(16) bf16 Bl[3][BN * BK];  // 3 x  8 KB

    const int t = threadIdx.x;
    const int wave = t >> 6, lane = t & 63;
    const int wr = wave >> 1, wc = wave & 1;     // 4x2 wave grid
    const int lr = lane & 15, quad = lane >> 4;  // MFMA lane decomposition

    // XCD-chunked bijective swizzle; x-fast within a chunk => same-A blocks
    // run consecutively on the same XCD.
    const int lin = blockIdx.y * GRID_X + blockIdx.x;
    const int swz = (lin & 7) * WG_PER_XCD + (lin >> 3);
    const int bx  = swz % GRID_X;
    const int by  = swz / GRID_X;
    const long m0 = (long)by * BM;
    const int  n0 = bx * BN;

    // Staging sources (pre-swizzled global addresses; LDS stays linear).
    // Slot e (16B units): row = e>>2, slot_chunk = e&3 holds global chunk
    // gc = (e&3) ^ ((row>>1)&3). A: 1024 slots (2 insts), B: 512 (1 inst).
    const int e1 = 512 + t;
    const int r0 = t >> 2, r1 = e1 >> 2;
    const int c0 = (t & 3) ^ ((r0 >> 1) & 3);
    const int c1 = (e1 & 3) ^ ((r1 >> 1) & 3);
    const bf16* gA0 = A + (m0 + r0) * K_DIM + c0 * 8;
    const bf16* gA1 = A + (m0 + r1) * K_DIM + c1 * 8;
    const bf16* gB0 = B + (long)(n0 + r0) * K_DIM + c0 * 8;

    const int ldsOff0 = (wave * 64) * 16;        // wave-uniform dest (bytes)
    const int ldsOff1 = (512 + wave * 64) * 16;

#define STAGE(slot, kb)                                                   \
    do {                                                                  \
        async_copy16(gA0 + (kb) * BK, (char*)Al[slot] + ldsOff0);         \
        async_copy16(gA1 + (kb) * BK, (char*)Al[slot] + ldsOff1);         \
        async_copy16(gB0 + (kb) * BK, (char*)Bl[slot] + ldsOff0);         \
    } while (0)

    f32x4 acc[4][4];
#pragma unroll
    for (int i = 0; i < 4; ++i)
#pragma unroll
        for (int j = 0; j < 4; ++j)
            acc[i][j] = (f32x4){0.f, 0.f, 0.f, 0.f};

    // LDS read offsets: row r reads chunk quad swizzled by ((r>>1)&3);
    // 16-row fragment bases are multiples of 16 so only lr enters the XOR.
    const int sw   = (quad ^ ((lr >> 1) & 3)) * 8;
    const int aoff = (wr * 64 + lr) * BK + sw;
    const int boff = (wc * 64 + lr) * BK + sw;

    // Prologue: tiles 0,1 in flight; wait tile 0 (3 newer loads allowed).
    STAGE(0, 0);
    STAGE(1, 1);
    asm volatile("s_waitcnt vmcnt(3)" ::: "memory");
    __builtin_amdgcn_s_barrier();

#pragma unroll
    for (int kb = 0; kb < NKT; ++kb) {
        if (kb + 2 < NKT) STAGE((kb + 2) % 3, kb + 2);

        const bf16* Ab = Al[kb % 3] + aoff;
        const bf16* Bb = Bl[kb % 3] + boff;
        bf16x8 a[4], b[4];
#pragma unroll
        for (int i = 0; i < 4; ++i) a[i] = *(const bf16x8*)(Ab + i * 16 * BK);
#pragma unroll
        for (int j = 0; j < 4; ++j) b[j] = *(const bf16x8*)(Bb + j * 16 * BK);

        __builtin_amdgcn_s_setprio(1);
#pragma unroll
        for (int i = 0; i < 4; ++i)
#pragma unroll
            for (int j = 0; j < 4; ++j)
                acc[i][j] = __builtin_amdgcn_mfma_f32_16x16x32_bf16(
                    a[i], b[j], acc[i][j], 0, 0, 0);
        __builtin_amdgcn_s_setprio(0);

        // Boundary: ensure tile kb+1 landed; keep kb+2's loads in flight.
        if (kb + 2 < NKT) {
            asm volatile("s_waitcnt vmcnt(3)" ::: "memory");
        } else if (kb + 1 < NKT) {
            asm volatile("s_waitcnt vmcnt(0)" ::: "memory");
        }
        if (kb + 1 < NKT) __builtin_amdgcn_s_barrier();
    }
#undef STAGE

    // Epilogue: C/D layout col = lane&15, row = quad*4 + reg [m89/m91].
    float bb[4];
#pragma unroll
    for (int j = 0; j < 4; ++j) bb[j] = bias[n0 + wc * 64 + j * 16 + lr];

#pragma unroll
    for (int i = 0; i < 4; ++i) {
        const long grow0 = m0 + wr * 64 + i * 16 + quad * 4;
#pragma unroll
        for (int j = 0; j < 4; ++j) {
            const int gcol = n0 + wc * 64 + j * 16 + lr;
#pragma unroll
            for (int r = 0; r < 4; ++r) {
                const float y = acc[i][j][r] + bb[j];
                __builtin_nontemporal_store(
                    gelu_exact(y), &out[(grow0 + r) * (long)N_DIM + gcol]);
            }
        }
    }
}

extern "C" void kernel_launch(void* const* d_in, const int* in_sizes, int n_in,
                              void* d_out, int out_size, void* d_ws, size_t ws_size,
                              hipStream_t stream) {
    (void)in_sizes; (void)n_in; (void)out_size; (void)ws_size;
    const float* x     = (const float*)d_in[0];
    const float* gamma = (const float*)d_in[1];
    const float* beta  = (const float*)d_in[2];
    const float* W     = (const float*)d_in[3];
    const float* b     = (const float*)d_in[4];
    float* out = (float*)d_out;

    // Workspace layout: xn bf16 [M][K] then Wb bf16 [N][K] (~39.7 MB total).
    bf16* xn = (bf16*)d_ws;
    bf16* Wb = (bf16*)((char*)d_ws + (size_t)M_ROWS * K_DIM * sizeof(bf16));

    ln_kernel<<<M_ROWS / 4, 256, 0, stream>>>(x, gamma, beta, xn);
    wcvt_kernel<<<(N_DIM * K_DIM / 2) / 256, 256, 0, stream>>>(W, Wb);

    dim3 grid(GRID_X, GRID_Y);
    gemm_kernel<<<grid, 512, 0, stream>>>(xn, Wb, b, out);
}